// Round 3
// baseline (27336.835 us; speedup 1.0000x reference)
//
#include <hip/hip_runtime.h>
#include <math.h>

#define S_LEN 64
#define T_LEN 64
#define BSZ   32
#define EDIM  512
#define HDIM  1024
#define VDIM  32000
#define FOURH 4096

#define NBLK  256
#define TPB   512   // 8 waves/block -> 2048 waves total

typedef __attribute__((ext_vector_type(8))) short  short8;
typedef __attribute__((ext_vector_type(4))) float  floatx4;

__device__ __forceinline__ unsigned short f2bf(float x){
  unsigned u = __float_as_uint(x);
  u = (u + 0x7FFFu + ((u >> 16) & 1u)) >> 16;
  return (unsigned short)u;
}
__device__ __forceinline__ float sigm(float x){ return 1.f/(1.f+__expf(-x)); }

__device__ __forceinline__ float allred(float s){
  #pragma unroll
  for (int off=1; off<64; off<<=1) s += __shfl_xor(s, off);
  return s;
}
__device__ __forceinline__ float allmax(float s){
  #pragma unroll
  for (int off=1; off<64; off<<=1) s = fmaxf(s, __shfl_xor(s, off));
  return s;
}

// ---- device-scope grid barrier (sense-reversing, generation counter) ----
// Co-residency guaranteed by construction: 256 blocks x 8 waves, VGPR<=256
// => exactly 1 block/CU fits => all blocks resident.
__device__ __forceinline__ void gbar(unsigned* cnt, unsigned* gen){
  __syncthreads();                       // drains this block's stores (vmcnt 0)
  if (threadIdx.x == 0){
    __threadfence();                     // release: write back XCD L2 to coherence point
    unsigned g = __hip_atomic_load(gen, __ATOMIC_RELAXED, __HIP_MEMORY_SCOPE_AGENT);
    unsigned a = __hip_atomic_fetch_add(cnt, 1u, __ATOMIC_ACQ_REL, __HIP_MEMORY_SCOPE_AGENT);
    if (a == (unsigned)(NBLK-1)){
      __hip_atomic_store(cnt, 0u, __ATOMIC_RELAXED, __HIP_MEMORY_SCOPE_AGENT);
      __hip_atomic_fetch_add(gen, 1u, __ATOMIC_RELEASE, __HIP_MEMORY_SCOPE_AGENT);
    } else {
      long it = 0;
      while (__hip_atomic_load(gen, __ATOMIC_RELAXED, __HIP_MEMORY_SCOPE_AGENT) == g){
        __builtin_amdgcn_s_sleep(1);
        if (++it > (1L<<20)) break;      // safety: fail visibly instead of hanging
      }
    }
    __threadfence();                     // acquire: invalidate stale lines for this CU
  }
  __syncthreads();
}

// ---------------- fp32 -> bf16 conversion (vectorized, grid-stride) ----------------
__global__ void cvt_bf16_v4(const float* __restrict__ in, unsigned short* __restrict__ out, long n4){
  long i = (long)blockIdx.x*blockDim.x + threadIdx.x;
  long stride = (long)gridDim.x*blockDim.x;
  for (; i < n4; i += stride){
    float4 v = ((const float4*)in)[i];
    ushort4 o; o.x=f2bf(v.x); o.y=f2bf(v.y); o.z=f2bf(v.z); o.w=f2bf(v.w);
    ((ushort4*)out)[i] = o;
  }
}

// ---------------- embedding gather -> bf16 rows [rows][EDIM] ----------------
__global__ void embed_gather(const int* __restrict__ toks, const float* __restrict__ emb,
                             unsigned short* __restrict__ out, int total4){
  int i = blockIdx.x*blockDim.x + threadIdx.x;
  if (i >= total4) return;
  const int e4 = EDIM/4;
  int r = i / e4, e = (i % e4)*4;
  int tok = toks[r];
  float4 v = *(const float4*)(emb + (size_t)tok*EDIM + e);
  ushort4 o; o.x=f2bf(v.x); o.y=f2bf(v.y); o.z=f2bf(v.z); o.w=f2bf(v.w);
  *(ushort4*)(out + (size_t)r*EDIM + e) = o;
}

// ---------------- target token per projection row ----------------
__global__ void tok_row_kernel(const int* __restrict__ tgt, int* __restrict__ tokRow){
  int r = blockIdx.x*blockDim.x + threadIdx.x;
  if (r >= T_LEN*BSZ) return;
  int t = r >> 5, b = r & 31;
  tokRow[r] = (t < T_LEN-1) ? tgt[(t+1)*BSZ + b] : -1;
}

// ---------------- bf16 MFMA GEMM: C[M,N] = A[M,K] * W[N,K]^T (+bias) ----------------
template<int EPI>
__global__ __launch_bounds__(256,1) void gemm_mfma(
    const unsigned short* __restrict__ A, int lda,
    const unsigned short* __restrict__ W, int ldw,
    const float* __restrict__ bias,
    float* __restrict__ C, int ldc, int K,
    float* __restrict__ rowSum, float* __restrict__ logitTgt, const int* __restrict__ tokRow)
{
  __shared__ unsigned short As[128*32];
  __shared__ unsigned short Ws[128*32];
  const int tid  = threadIdx.x;
  const int wave = tid >> 6, lane = tid & 63;
  const int bm = blockIdx.x * 128, bn = blockIdx.y * 128;
  const int wr = (wave >> 1) * 64, wc = (wave & 1) * 64;
  const int srow = tid >> 2, scol = (tid & 3) * 8;
  const int rg = (lane >> 4) * 8, rl = lane & 15;
  floatx4 acc[4][4] = {};

  for (int kt = 0; kt < K; kt += 32){
    short8 a0 = *(const short8*)(A + (size_t)(bm + srow)*lda      + kt + scol);
    short8 a1 = *(const short8*)(A + (size_t)(bm + 64 + srow)*lda + kt + scol);
    short8 w0 = *(const short8*)(W + (size_t)(bn + srow)*ldw      + kt + scol);
    short8 w1 = *(const short8*)(W + (size_t)(bn + 64 + srow)*ldw + kt + scol);
    __syncthreads();
    *(short8*)&As[srow*32 + scol]      = a0;
    *(short8*)&As[(64+srow)*32 + scol] = a1;
    *(short8*)&Ws[srow*32 + scol]      = w0;
    *(short8*)&Ws[(64+srow)*32 + scol] = w1;
    __syncthreads();
    short8 af[4], wf[4];
    #pragma unroll
    for (int m=0;m<4;m++) af[m] = *(const short8*)&As[(wr + m*16 + rl)*32 + rg];
    #pragma unroll
    for (int n=0;n<4;n++) wf[n] = *(const short8*)&Ws[(wc + n*16 + rl)*32 + rg];
    #pragma unroll
    for (int m=0;m<4;m++)
      #pragma unroll
      for (int n=0;n<4;n++)
        acc[m][n] = __builtin_amdgcn_mfma_f32_16x16x32_bf16(af[m], wf[n], acc[m][n], 0, 0, 0);
  }

  if (EPI == 0){
    float bv[4];
    #pragma unroll
    for (int n=0;n<4;n++) bv[n] = bias[bn + wc + n*16 + rl];
    #pragma unroll
    for (int m=0;m<4;m++){
      #pragma unroll
      for (int j=0;j<4;j++){
        int r = bm + wr + m*16 + (lane>>4)*4 + j;
        #pragma unroll
        for (int n=0;n<4;n++){
          int c = bn + wc + n*16 + rl;
          C[(size_t)r*ldc + c] = acc[m][n][j] + bv[n];
        }
      }
    }
  } else {
    #pragma unroll
    for (int m=0;m<4;m++){
      #pragma unroll
      for (int j=0;j<4;j++){
        int r = bm + wr + m*16 + (lane>>4)*4 + j;
        int tok = tokRow[r];
        float esum = 0.f;
        #pragma unroll
        for (int n=0;n<4;n++){
          int c = bn + wc + n*16 + rl;
          float v = acc[m][n][j];
          if (c == tok) logitTgt[r] = v;
          esum += __expf(v);
        }
        esum += __shfl_xor(esum, 1);
        esum += __shfl_xor(esum, 2);
        esum += __shfl_xor(esum, 4);
        esum += __shfl_xor(esum, 8);
        if (rl == 0) atomicAdd(&rowSum[r], esum);
      }
    }
  }
}

// ---------------- persistent encoder+decoder megakernel ----------------
// 256 blocks x 512 threads; phases separated by device-scope grid barriers.
// States h0,c0,h1,c1 are updated IN-PLACE (phase barriers make this safe);
// encoder finals become decoder initial states for free.
__global__ __launch_bounds__(TPB, 2) void megakernel(
    const float* __restrict__ preZe, const float* __restrict__ preZd,
    const float* __restrict__ eW_hh0,
    const float* __restrict__ eW_ih1, const float* __restrict__ eW_hh1, const float* __restrict__ eb1,
    const float* __restrict__ dW_ih0, const float* __restrict__ dW_hh0,
    const float* __restrict__ dW_ih1, const float* __restrict__ dW_hh1, const float* __restrict__ db1,
    const float* __restrict__ Wht, const float* __restrict__ w2pt, const float* __restrict__ Wct,
    const int* __restrict__ elen,
    float* __restrict__ h0, float* __restrict__ c0,
    float* __restrict__ h1, float* __restrict__ c1,
    float* __restrict__ h0t, float* __restrict__ c0t,
    float* __restrict__ ht,  float* __restrict__ ench,
    float* __restrict__ tanv, float* __restrict__ scores, float* __restrict__ ct,
    unsigned short* __restrict__ decoutb,
    unsigned* cnt, unsigned* gen)
{
  const int tid  = threadIdx.x;
  const int lane = tid & 63;
  const int gw   = blockIdx.x*(TPB/64) + (tid >> 6);   // 0..2047
  const int j    = gw >> 1;                            // hidden unit 0..1023
  const int bb   = (gw & 1) * 16;                      // batch half

  // =============== encoder ===============
  for (int t = 0; t < S_LEN; t++){
    // ---- E0: z0 = preZe + h0*Whh0^T -> (h0t, c0t) ----
    {
      float4 w[4][4];
      #pragma unroll
      for (int g=0; g<4; g++){
        const float* r = eW_hh0 + ((size_t)(g*HDIM + j))*HDIM + lane*16;
        #pragma unroll
        for (int q=0;q<4;q++) w[g][q] = *(const float4*)(r + q*4);
      }
      for (int ib=0; ib<16; ib++){
        const int b = bb + ib;
        float pz0=0,pz1=0,pz2=0,pz3=0,cv=0;
        if (lane == 0){
          const float* pz = preZe + ((size_t)(t*BSZ + b))*FOURH + j;
          pz0 = pz[0]; pz1 = pz[HDIM]; pz2 = pz[2*HDIM]; pz3 = pz[3*HDIM];
          cv = c0[b*HDIM + j];
        }
        const float* hp = h0 + b*HDIM + lane*16;
        float4 hv[4];
        #pragma unroll
        for (int q=0;q<4;q++) hv[q] = *(const float4*)(hp + q*4);
        float s0=0,s1=0,s2=0,s3=0;
        #pragma unroll
        for (int q=0;q<4;q++){
          s0 += w[0][q].x*hv[q].x + w[0][q].y*hv[q].y + w[0][q].z*hv[q].z + w[0][q].w*hv[q].w;
          s1 += w[1][q].x*hv[q].x + w[1][q].y*hv[q].y + w[1][q].z*hv[q].z + w[1][q].w*hv[q].w;
          s2 += w[2][q].x*hv[q].x + w[2][q].y*hv[q].y + w[2][q].z*hv[q].z + w[2][q].w*hv[q].w;
          s3 += w[3][q].x*hv[q].x + w[3][q].y*hv[q].y + w[3][q].z*hv[q].z + w[3][q].w*hv[q].w;
        }
        s0 = allred(s0); s1 = allred(s1); s2 = allred(s2); s3 = allred(s3);
        if (lane == 0){
          float cc = sigm(pz1+s1)*cv + sigm(pz0+s0)*tanhf(pz2+s2);
          float hh = sigm(pz3+s3)*tanhf(cc);
          h0t[b*HDIM+j] = hh; c0t[b*HDIM+j] = cc;
        }
      }
    }
    gbar(cnt, gen);
    // ---- E1: z1 = b1 + h0t*Wih1^T + h1*Whh1^T -> masked commit ----
    {
      float4 wi[4][4], wh[4][4];
      #pragma unroll
      for (int g=0; g<4; g++){
        const float* r1 = eW_ih1 + ((size_t)(g*HDIM + j))*HDIM + lane*16;
        const float* r2 = eW_hh1 + ((size_t)(g*HDIM + j))*HDIM + lane*16;
        #pragma unroll
        for (int q=0;q<4;q++){ wi[g][q] = *(const float4*)(r1 + q*4); wh[g][q] = *(const float4*)(r2 + q*4); }
      }
      float b0=0,b1=0,b2=0,b3=0;
      if (lane == 0){ b0=eb1[j]; b1=eb1[HDIM+j]; b2=eb1[2*HDIM+j]; b3=eb1[3*HDIM+j]; }
      for (int ib=0; ib<16; ib++){
        const int b = bb + ib;
        float c1v=0, h0tv=0, c0tv=0; int lenb=0;
        if (lane == 0){
          size_t bi = (size_t)b*HDIM + j;
          c1v = c1[bi]; h0tv = h0t[bi]; c0tv = c0t[bi]; lenb = elen[b];
        }
        const float* xp = h0t + b*HDIM + lane*16;
        const float* hp = h1  + b*HDIM + lane*16;
        float4 xv[4], hv[4];
        #pragma unroll
        for (int q=0;q<4;q++){ xv[q] = *(const float4*)(xp + q*4); hv[q] = *(const float4*)(hp + q*4); }
        float s0=0,s1=0,s2=0,s3=0;
        #pragma unroll
        for (int q=0;q<4;q++){
          s0 += wi[0][q].x*xv[q].x + wi[0][q].y*xv[q].y + wi[0][q].z*xv[q].z + wi[0][q].w*xv[q].w
              + wh[0][q].x*hv[q].x + wh[0][q].y*hv[q].y + wh[0][q].z*hv[q].z + wh[0][q].w*hv[q].w;
          s1 += wi[1][q].x*xv[q].x + wi[1][q].y*xv[q].y + wi[1][q].z*xv[q].z + wi[1][q].w*xv[q].w
              + wh[1][q].x*hv[q].x + wh[1][q].y*hv[q].y + wh[1][q].z*hv[q].z + wh[1][q].w*hv[q].w;
          s2 += wi[2][q].x*xv[q].x + wi[2][q].y*xv[q].y + wi[2][q].z*xv[q].z + wi[2][q].w*xv[q].w
              + wh[2][q].x*hv[q].x + wh[2][q].y*hv[q].y + wh[2][q].z*hv[q].z + wh[2][q].w*hv[q].w;
          s3 += wi[3][q].x*xv[q].x + wi[3][q].y*xv[q].y + wi[3][q].z*xv[q].z + wi[3][q].w*xv[q].w
              + wh[3][q].x*hv[q].x + wh[3][q].y*hv[q].y + wh[3][q].z*hv[q].z + wh[3][q].w*hv[q].w;
        }
        s0 = allred(s0); s1 = allred(s1); s2 = allred(s2); s3 = allred(s3);
        if (lane == 0){
          float cc = sigm(b1+s1)*c1v + sigm(b0+s0)*tanhf(b2+s2);
          float hh = sigm(b3+s3)*tanhf(cc);
          size_t bi = (size_t)b*HDIM + j;
          float eout = 0.f;
          if (t < lenb){
            h1[bi] = hh; c1[bi] = cc; h0[bi] = h0tv; c0[bi] = c0tv;
            eout = hh;
          }
          ench[((size_t)t*BSZ + b)*HDIM + j] = eout;
        }
      }
    }
    gbar(cnt, gen);
  }

  // =============== decoder ===============
  for (int t = 0; t < T_LEN; t++){
    // ---- D0: z0 = preZd + ht*Wih0[:,E:]^T + h0*Whh0^T -> (h0t, c0t) ----
    {
      float4 wi[4][4], wh[4][4];
      #pragma unroll
      for (int g=0; g<4; g++){
        const float* r1 = dW_ih0 + ((size_t)(g*HDIM + j))*(EDIM+HDIM) + EDIM + lane*16;
        const float* r2 = dW_hh0 + ((size_t)(g*HDIM + j))*HDIM + lane*16;
        #pragma unroll
        for (int q=0;q<4;q++){ wi[g][q] = *(const float4*)(r1 + q*4); wh[g][q] = *(const float4*)(r2 + q*4); }
      }
      for (int ib=0; ib<16; ib++){
        const int b = bb + ib;
        float pz0=0,pz1=0,pz2=0,pz3=0,cv=0;
        if (lane == 0){
          const float* pz = preZd + ((size_t)(t*BSZ + b))*FOURH + j;
          pz0 = pz[0]; pz1 = pz[HDIM]; pz2 = pz[2*HDIM]; pz3 = pz[3*HDIM];
          cv = c0[b*HDIM + j];
        }
        const float* xp = ht + b*HDIM + lane*16;
        const float* hp = h0 + b*HDIM + lane*16;
        float4 xv[4], hv[4];
        #pragma unroll
        for (int q=0;q<4;q++){ xv[q] = *(const float4*)(xp + q*4); hv[q] = *(const float4*)(hp + q*4); }
        float s0=0,s1=0,s2=0,s3=0;
        #pragma unroll
        for (int q=0;q<4;q++){
          s0 += wi[0][q].x*xv[q].x + wi[0][q].y*xv[q].y + wi[0][q].z*xv[q].z + wi[0][q].w*xv[q].w
              + wh[0][q].x*hv[q].x + wh[0][q].y*hv[q].y + wh[0][q].z*hv[q].z + wh[0][q].w*hv[q].w;
          s1 += wi[1][q].x*xv[q].x + wi[1][q].y*xv[q].y + wi[1][q].z*xv[q].z + wi[1][q].w*xv[q].w
              + wh[1][q].x*hv[q].x + wh[1][q].y*hv[q].y + wh[1][q].z*hv[q].z + wh[1][q].w*hv[q].w;
          s2 += wi[2][q].x*xv[q].x + wi[2][q].y*xv[q].y + wi[2][q].z*xv[q].z + wi[2][q].w*xv[q].w
              + wh[2][q].x*hv[q].x + wh[2][q].y*hv[q].y + wh[2][q].z*hv[q].z + wh[2][q].w*hv[q].w;
          s3 += wi[3][q].x*xv[q].x + wi[3][q].y*xv[q].y + wi[3][q].z*xv[q].z + wi[3][q].w*xv[q].w
              + wh[3][q].x*hv[q].x + wh[3][q].y*hv[q].y + wh[3][q].z*hv[q].z + wh[3][q].w*hv[q].w;
        }
        s0 = allred(s0); s1 = allred(s1); s2 = allred(s2); s3 = allred(s3);
        if (lane == 0){
          float cc = sigm(pz1+s1)*cv + sigm(pz0+s0)*tanhf(pz2+s2);
          float hh = sigm(pz3+s3)*tanhf(cc);
          h0t[b*HDIM+j] = hh; c0t[b*HDIM+j] = cc;
        }
      }
    }
    gbar(cnt, gen);
    // ---- D1: z1 = b1 + h0t*Wih1^T + h1*Whh1^T -> commit (h1 is yt) ----
    {
      float4 wi[4][4], wh[4][4];
      #pragma unroll
      for (int g=0; g<4; g++){
        const float* r1 = dW_ih1 + ((size_t)(g*HDIM + j))*HDIM + lane*16;
        const float* r2 = dW_hh1 + ((size_t)(g*HDIM + j))*HDIM + lane*16;
        #pragma unroll
        for (int q=0;q<4;q++){ wi[g][q] = *(const float4*)(r1 + q*4); wh[g][q] = *(const float4*)(r2 + q*4); }
      }
      float b0=0,b1=0,b2=0,b3=0;
      if (lane == 0){ b0=db1[j]; b1=db1[HDIM+j]; b2=db1[2*HDIM+j]; b3=db1[3*HDIM+j]; }
      for (int ib=0; ib<16; ib++){
        const int b = bb + ib;
        float c1v=0, h0tv=0, c0tv=0;
        if (lane == 0){
          size_t bi = (size_t)b*HDIM + j;
          c1v = c1[bi]; h0tv = h0t[bi]; c0tv = c0t[bi];
        }
        const float* xp = h0t + b*HDIM + lane*16;
        const float* hp = h1  + b*HDIM + lane*16;
        float4 xv[4], hv[4];
        #pragma unroll
        for (int q=0;q<4;q++){ xv[q] = *(const float4*)(xp + q*4); hv[q] = *(const float4*)(hp + q*4); }
        float s0=0,s1=0,s2=0,s3=0;
        #pragma unroll
        for (int q=0;q<4;q++){
          s0 += wi[0][q].x*xv[q].x + wi[0][q].y*xv[q].y + wi[0][q].z*xv[q].z + wi[0][q].w*xv[q].w
              + wh[0][q].x*hv[q].x + wh[0][q].y*hv[q].y + wh[0][q].z*hv[q].z + wh[0][q].w*hv[q].w;
          s1 += wi[1][q].x*xv[q].x + wi[1][q].y*xv[q].y + wi[1][q].z*xv[q].z + wi[1][q].w*xv[q].w
              + wh[1][q].x*hv[q].x + wh[1][q].y*hv[q].y + wh[1][q].z*hv[q].z + wh[1][q].w*hv[q].w;
          s2 += wi[2][q].x*xv[q].x + wi[2][q].y*xv[q].y + wi[2][q].z*xv[q].z + wi[2][q].w*xv[q].w
              + wh[2][q].x*hv[q].x + wh[2][q].y*hv[q].y + wh[2][q].z*hv[q].z + wh[2][q].w*hv[q].w;
          s3 += wi[3][q].x*xv[q].x + wi[3][q].y*xv[q].y + wi[3][q].z*xv[q].z + wi[3][q].w*xv[q].w
              + wh[3][q].x*hv[q].x + wh[3][q].y*hv[q].y + wh[3][q].z*hv[q].z + wh[3][q].w*hv[q].w;
        }
        s0 = allred(s0); s1 = allred(s1); s2 = allred(s2); s3 = allred(s3);
        if (lane == 0){
          float cc = sigm(b1+s1)*c1v + sigm(b0+s0)*tanhf(b2+s2);
          float hh = sigm(b3+s3)*tanhf(cc);
          size_t bi = (size_t)b*HDIM + j;
          h1[bi] = hh; c1[bi] = cc; h0[bi] = h0tv; c0[bi] = c0tv;
        }
      }
    }
    gbar(cnt, gen);
    // ---- A: tanv = tanh(yt*Wht^T); scores[b,s] (masked) ----
    {
      // job2: one (b,s) pair per wave
      {
        const int b2 = gw >> 6, s2 = gw & 63;
        int lenb = 0;
        if (lane == 0) lenb = elen[b2];
        const float* yp = h1 + b2*HDIM + lane*16;
        const float* ep = ench + ((size_t)s2*BSZ + b2)*HDIM + lane*16;
        float s = 0;
        #pragma unroll
        for (int q=0;q<4;q++){
          float4 yv = *(const float4*)(yp + q*4);
          float4 ev = *(const float4*)(ep + q*4);
          s += yv.x*ev.x + yv.y*ev.y + yv.z*ev.z + yv.w*ev.w;
        }
        s = allred(s);
        if (lane == 0) scores[b2*S_LEN + s2] = (s2 < lenb) ? s : -1e30f;
      }
      // job1: tanv for unit j, 16 batches
      {
        float4 w[4];
        #pragma unroll
        for (int q=0;q<4;q++) w[q] = *(const float4*)(Wht + (size_t)j*HDIM + lane*16 + q*4);
        for (int ib=0; ib<16; ib++){
          const int b = bb + ib;
          const float* hp = h1 + b*HDIM + lane*16;
          float s = 0;
          #pragma unroll
          for (int q=0;q<4;q++){
            float4 hv = *(const float4*)(hp + q*4);
            s += w[q].x*hv.x + w[q].y*hv.y + w[q].z*hv.z + w[q].w*hv.w;
          }
          s = allred(s);
          if (lane == 0) tanv[b*HDIM + j] = tanhf(s);
        }
      }
    }
    gbar(cnt, gen);
    // ---- B: pt + softmax + window -> ct  (512 waves: b x 16 h-chunks) ----
    if (gw < 512){
      const int b = gw >> 4;
      const int hb = (gw & 15) * 64;
      // pt (redundant per h-chunk wave; trivial cost)
      float part = 0;
      const float* tv = tanv + b*HDIM + lane*16;
      const float* wp = w2pt + lane*16;
      #pragma unroll
      for (int q=0;q<4;q++){
        float4 a = *(const float4*)(tv + q*4);
        float4 c = *(const float4*)(wp + q*4);
        part += a.x*c.x + a.y*c.y + a.z*c.z + a.w*c.w;
      }
      part = allred(part);
      float ptv = sigm(part) * (float)elen[b];
      // softmax + window, lane = s
      float sc = scores[b*S_LEN + lane];
      float m = allmax(sc);
      float e = __expf(sc - m);
      float ssum = allred(e);
      float d = (float)lane - ptv;
      float atl = (e/ssum) * __expf(-(d*d)*0.02f);   // 1/(WIN_D^2/2) = 1/50
      // ct[b][hb+lane] = sum_s at[s] * ench[s][b][hb+lane]
      float acc = 0;
      #pragma unroll 4
      for (int s = 0; s < S_LEN; s++){
        float a = __shfl(atl, s);
        acc += a * ench[((size_t)s*BSZ + b)*HDIM + hb + lane];
      }
      ct[b*HDIM + hb + lane] = acc;
    }
    gbar(cnt, gen);
    // ---- C: ht = tanh(cat(ct,yt)*Wct^T); decout bf16 ----
    {
      float4 wc_[4], wy_[4];
      #pragma unroll
      for (int q=0;q<4;q++){
        wc_[q] = *(const float4*)(Wct + (size_t)j*(2*HDIM) + lane*16 + q*4);
        wy_[q] = *(const float4*)(Wct + (size_t)j*(2*HDIM) + HDIM + lane*16 + q*4);
      }
      for (int ib=0; ib<16; ib++){
        const int b = bb + ib;
        const float* cp = ct + b*HDIM + lane*16;
        const float* yp = h1 + b*HDIM + lane*16;
        float s = 0;
        #pragma unroll
        for (int q=0;q<4;q++){
          float4 cv = *(const float4*)(cp + q*4);
          float4 yv = *(const float4*)(yp + q*4);
          s += wc_[q].x*cv.x + wc_[q].y*cv.y + wc_[q].z*cv.z + wc_[q].w*cv.w
             + wy_[q].x*yv.x + wy_[q].y*yv.y + wy_[q].z*yv.z + wy_[q].w*yv.w;
        }
        s = allred(s);
        if (lane == 0){
          float v = tanhf(s);
          ht[(size_t)b*HDIM + j] = v;
          decoutb[((size_t)t*BSZ + b)*HDIM + j] = f2bf(v);
        }
      }
    }
    gbar(cnt, gen);
  }
}

// ---------------- final loss ----------------
__global__ void loss_kernel(const float* __restrict__ rowSum, const float* __restrict__ logitTgt,
                            const int* __restrict__ tgt, float* __restrict__ out)
{
  const int b = blockIdx.x, t = threadIdx.x;  // 64 threads
  float v = 0.f;
  if (t < T_LEN-1){
    int r = t*BSZ + b;
    if (tgt[(t+1)*BSZ + b] != 0) v = logitTgt[r] - logf(rowSum[r]);
  }
  #pragma unroll
  for (int off=1; off<64; off<<=1) v += __shfl_xor(v, off);
  if (t == 0) out[b] = v;
}

// =====================================================================================
extern "C" void kernel_launch(void* const* d_in, const int* in_sizes, int n_in,
                              void* d_out, int out_size, void* d_ws, size_t ws_size,
                              hipStream_t stream)
{
  const int*   src_tokens = (const int*)d_in[0];
  const int*   tgt_tokens = (const int*)d_in[1];
  const int*   encode_len = (const int*)d_in[2];
  const float* emb_src  = (const float*)d_in[3];
  const float* emb_tar  = (const float*)d_in[4];
  const float* eW_ih0   = (const float*)d_in[5];
  const float* eW_hh0   = (const float*)d_in[6];
  const float* eb0      = (const float*)d_in[7];
  const float* eW_ih1   = (const float*)d_in[8];
  const float* eW_hh1   = (const float*)d_in[9];
  const float* eb1      = (const float*)d_in[10];
  const float* dW_ih0   = (const float*)d_in[11];
  const float* dW_hh0   = (const float*)d_in[12];
  const float* db0      = (const float*)d_in[13];
  const float* dW_ih1   = (const float*)d_in[14];
  const float* dW_hh1   = (const float*)d_in[15];
  const float* db1      = (const float*)d_in[16];
  const float* W_ht2tan = (const float*)d_in[17];
  const float* w_tan2pt = (const float*)d_in[18];
  const float* W_ct2ht  = (const float*)d_in[19];
  const float* W_final  = (const float*)d_in[20];
  float* out = (float*)d_out;

  char* wsp = (char*)d_ws;
  auto alloc = [&](size_t bytes)->void*{
    void* p = (void*)wsp; wsp += ((bytes + 255) & ~(size_t)255); return p;
  };
  float* preZe = (float*)alloc(2048ull*4096*4);
  float* preZd = (float*)alloc(2048ull*4096*4);
  float* ench  = (float*)alloc((size_t)S_LEN*BSZ*HDIM*4);
  float* h0    = (float*)alloc((size_t)BSZ*HDIM*4);
  float* c0    = (float*)alloc((size_t)BSZ*HDIM*4);
  float* h1    = (float*)alloc((size_t)BSZ*HDIM*4);
  float* c1    = (float*)alloc((size_t)BSZ*HDIM*4);
  float* ht    = (float*)alloc((size_t)BSZ*HDIM*4);
  float* h0t   = (float*)alloc((size_t)BSZ*HDIM*4);
  float* c0t   = (float*)alloc((size_t)BSZ*HDIM*4);
  float* tanv  = (float*)alloc((size_t)BSZ*HDIM*4);
  float* ctb   = (float*)alloc((size_t)BSZ*HDIM*4);
  float* scores= (float*)alloc((size_t)BSZ*S_LEN*4);
  float* rowSum   = (float*)alloc(2048*4);
  float* logitTgt = (float*)alloc(2048*4);
  int*   tokRow   = (int*)alloc(2048*4);
  unsigned* barws = (unsigned*)alloc(256);
  unsigned short* xsrc    = (unsigned short*)alloc(2048ull*EDIM*2);
  unsigned short* ytgt    = (unsigned short*)alloc(2048ull*EDIM*2);
  unsigned short* eWih0b  = (unsigned short*)alloc((size_t)FOURH*EDIM*2);
  unsigned short* dWih0b  = (unsigned short*)alloc((size_t)FOURH*(EDIM+HDIM)*2);
  unsigned short* Wfinb   = (unsigned short*)alloc((size_t)VDIM*HDIM*2);
  unsigned short* decoutb = (unsigned short*)alloc(2048ull*HDIM*2);

  const size_t ST = (size_t)BSZ*HDIM;

  // zero-init states + rowSum + barrier
  hipMemsetAsync(h0, 0, ST*4, stream);
  hipMemsetAsync(c0, 0, ST*4, stream);
  hipMemsetAsync(h1, 0, ST*4, stream);
  hipMemsetAsync(c1, 0, ST*4, stream);
  hipMemsetAsync(ht, 0, ST*4, stream);
  hipMemsetAsync(rowSum, 0, 2048*4, stream);
  hipMemsetAsync(barws, 0, 256, stream);

  // weight conversions + embedding gathers (parallel prework)
  cvt_bf16_v4<<<1024, 256, 0, stream>>>(eW_ih0, eWih0b, (long)FOURH*EDIM/4);
  cvt_bf16_v4<<<2048, 256, 0, stream>>>(dW_ih0, dWih0b, (long)FOURH*(EDIM+HDIM)/4);
  cvt_bf16_v4<<<4096, 256, 0, stream>>>(W_final, Wfinb, (long)VDIM*HDIM/4);
  embed_gather<<<(2048*EDIM/4 + 255)/256, 256, 0, stream>>>(src_tokens, emb_src, xsrc, 2048*EDIM/4);
  embed_gather<<<(2048*EDIM/4 + 255)/256, 256, 0, stream>>>(tgt_tokens, emb_tar, ytgt, 2048*EDIM/4);
  tok_row_kernel<<<8, 256, 0, stream>>>(tgt_tokens, tokRow);

  // input projections (bias fused)
  gemm_mfma<0><<<dim3(16,32), 256, 0, stream>>>(xsrc, EDIM, eWih0b, EDIM, eb0,
                                                preZe, FOURH, EDIM, nullptr, nullptr, nullptr);
  gemm_mfma<0><<<dim3(16,32), 256, 0, stream>>>(ytgt, EDIM, dWih0b, EDIM+HDIM, db0,
                                                preZd, FOURH, EDIM, nullptr, nullptr, nullptr);

  // persistent encoder + decoder (one launch, 448 grid barriers inside)
  megakernel<<<NBLK, TPB, 0, stream>>>(
      preZe, preZd, eW_hh0, eW_ih1, eW_hh1, eb1,
      dW_ih0, dW_hh0, dW_ih1, dW_hh1, db1,
      W_ht2tan, w_tan2pt, W_ct2ht, encode_len,
      h0, c0, h1, c1, h0t, c0t, ht, ench, tanv, scores, ctb, decoutb,
      barws + 0, barws + 32);

  // final projection + fused logsumexp
  gemm_mfma<1><<<dim3(16,250), 256, 0, stream>>>(decoutb, HDIM, Wfinb, HDIM, nullptr,
                                                 nullptr, 0, HDIM, rowSum, logitTgt, tokRow);
  loss_kernel<<<32, 64, 0, stream>>>(rowSum, logitTgt, tgt_tokens, out);
}

// Round 5
// 20169.402 us; speedup vs baseline: 1.3554x; 1.3554x over previous
//
#include <hip/hip_runtime.h>
#include <math.h>

#define S_LEN 64
#define T_LEN 64
#define BSZ   32
#define EDIM  512
#define HDIM  1024
#define VDIM  32000
#define FOURH 4096

#define NBLK  256
#define TPB   512   // 8 waves/block -> 2048 waves

typedef __attribute__((ext_vector_type(8))) short  short8;
typedef __attribute__((ext_vector_type(4))) float  floatx4;

__device__ __forceinline__ unsigned short f2bf(float x){
  unsigned u = __float_as_uint(x);
  u = (u + 0x7FFFu + ((u >> 16) & 1u)) >> 16;
  return (unsigned short)u;
}
__device__ __forceinline__ float bf2f(unsigned short u){
  return __uint_as_float(((unsigned)u) << 16);
}
__device__ __forceinline__ float sigm(float x){ return 1.f/(1.f+__expf(-x)); }

__device__ __forceinline__ float allred(float s){
  #pragma unroll
  for (int off=1; off<64; off<<=1) s += __shfl_xor(s, off);
  return s;
}
__device__ __forceinline__ float allmax(float s){
  #pragma unroll
  for (int off=1; off<64; off<<=1) s = fmaxf(s, __shfl_xor(s, off));
  return s;
}

// coherent (agent-scope, write-through) scalar store for cross-XCD state.
__device__ __forceinline__ void stc(float* p, float v){
  __hip_atomic_store(p, v, __ATOMIC_RELAXED, __HIP_MEMORY_SCOPE_AGENT);
}

// load 16 bf16 (one lane's k-slice) and unpack to 4 float4
__device__ __forceinline__ void ld16bf(const unsigned short* p, float4 w[4]){
  short8 s0 = *(const short8*)p;
  short8 s1 = *(const short8*)(p + 8);
  w[0].x=bf2f((unsigned short)s0[0]); w[0].y=bf2f((unsigned short)s0[1]);
  w[0].z=bf2f((unsigned short)s0[2]); w[0].w=bf2f((unsigned short)s0[3]);
  w[1].x=bf2f((unsigned short)s0[4]); w[1].y=bf2f((unsigned short)s0[5]);
  w[1].z=bf2f((unsigned short)s0[6]); w[1].w=bf2f((unsigned short)s0[7]);
  w[2].x=bf2f((unsigned short)s1[0]); w[2].y=bf2f((unsigned short)s1[1]);
  w[2].z=bf2f((unsigned short)s1[2]); w[2].w=bf2f((unsigned short)s1[3]);
  w[3].x=bf2f((unsigned short)s1[4]); w[3].y=bf2f((unsigned short)s1[5]);
  w[3].z=bf2f((unsigned short)s1[6]); w[3].w=bf2f((unsigned short)s1[7]);
}

// ---- device-scope grid barrier: NO cache maintenance (keeps L2 weight-resident).
// Cross-block data is exchanged via write-once agent-scope stores (stc) into
// per-step fresh slots + normal loads, so no L2 invalidation is needed here.
__device__ __forceinline__ void gbar(unsigned* cnt, unsigned* gen){
  asm volatile("s_waitcnt vmcnt(0) lgkmcnt(0)" ::: "memory");
  __syncthreads();
  if (threadIdx.x == 0){
    unsigned g = __hip_atomic_load(gen, __ATOMIC_RELAXED, __HIP_MEMORY_SCOPE_AGENT);
    unsigned a = __hip_atomic_fetch_add(cnt, 1u, __ATOMIC_RELAXED, __HIP_MEMORY_SCOPE_AGENT);
    if (a == (unsigned)(NBLK-1)){
      __hip_atomic_store(cnt, 0u, __ATOMIC_RELAXED, __HIP_MEMORY_SCOPE_AGENT);
      __hip_atomic_fetch_add(gen, 1u, __ATOMIC_RELAXED, __HIP_MEMORY_SCOPE_AGENT);
    } else {
      long it = 0;
      while (__hip_atomic_load(gen, __ATOMIC_RELAXED, __HIP_MEMORY_SCOPE_AGENT) == g){
        __builtin_amdgcn_s_sleep(2);
        if (++it > (1L<<22)) break;   // fail visibly instead of hanging
      }
    }
  }
  __syncthreads();
}

// ---------------- fp32 -> bf16 conversion (vectorized, grid-stride) ----------------
__global__ void cvt_bf16_v4(const float* __restrict__ in, unsigned short* __restrict__ out, long n4){
  long i = (long)blockIdx.x*blockDim.x + threadIdx.x;
  long stride = (long)gridDim.x*blockDim.x;
  for (; i < n4; i += stride){
    float4 v = ((const float4*)in)[i];
    ushort4 o; o.x=f2bf(v.x); o.y=f2bf(v.y); o.z=f2bf(v.z); o.w=f2bf(v.w);
    ((ushort4*)out)[i] = o;
  }
}

// strided variant (extract H-columns of dW_ih0)
__global__ void cvt_bf16_strided(const float* __restrict__ in, long inLD, long inOff,
                                 unsigned short* __restrict__ out, long outLD, long n4, long c4){
  long i = (long)blockIdx.x*blockDim.x + threadIdx.x;
  long stride = (long)gridDim.x*blockDim.x;
  for (; i < n4; i += stride){
    long r = i / c4, c = (i % c4)*4;
    float4 v = *(const float4*)(in + r*inLD + inOff + c);
    ushort4 o; o.x=f2bf(v.x); o.y=f2bf(v.y); o.z=f2bf(v.z); o.w=f2bf(v.w);
    *(ushort4*)(out + r*outLD + c) = o;
  }
}

// ---------------- embedding gather -> bf16 rows [rows][EDIM] ----------------
__global__ void embed_gather(const int* __restrict__ toks, const float* __restrict__ emb,
                             unsigned short* __restrict__ out, int total4){
  int i = blockIdx.x*blockDim.x + threadIdx.x;
  if (i >= total4) return;
  const int e4 = EDIM/4;
  int r = i / e4, e = (i % e4)*4;
  int tok = toks[r];
  float4 v = *(const float4*)(emb + (size_t)tok*EDIM + e);
  ushort4 o; o.x=f2bf(v.x); o.y=f2bf(v.y); o.z=f2bf(v.z); o.w=f2bf(v.w);
  *(ushort4*)(out + (size_t)r*EDIM + e) = o;
}

__global__ void tok_row_kernel(const int* __restrict__ tgt, int* __restrict__ tokRow){
  int r = blockIdx.x*blockDim.x + threadIdx.x;
  if (r >= T_LEN*BSZ) return;
  int t = r >> 5, b = r & 31;
  tokRow[r] = (t < T_LEN-1) ? tgt[(t+1)*BSZ + b] : -1;
}

// ---------------- bf16 MFMA GEMM: C[M,N] = A[M,K] * W[N,K]^T (+bias) ----------------
template<int EPI>
__global__ __launch_bounds__(256,1) void gemm_mfma(
    const unsigned short* __restrict__ A, int lda,
    const unsigned short* __restrict__ W, int ldw,
    const float* __restrict__ bias,
    float* __restrict__ C, int ldc, int K,
    float* __restrict__ rowSum, float* __restrict__ logitTgt, const int* __restrict__ tokRow)
{
  __shared__ unsigned short As[128*32];
  __shared__ unsigned short Ws[128*32];
  const int tid  = threadIdx.x;
  const int wave = tid >> 6, lane = tid & 63;
  const int bm = blockIdx.x * 128, bn = blockIdx.y * 128;
  const int wr = (wave >> 1) * 64, wc = (wave & 1) * 64;
  const int srow = tid >> 2, scol = (tid & 3) * 8;
  const int rg = (lane >> 4) * 8, rl = lane & 15;
  floatx4 acc[4][4] = {};

  for (int kt = 0; kt < K; kt += 32){
    short8 a0 = *(const short8*)(A + (size_t)(bm + srow)*lda      + kt + scol);
    short8 a1 = *(const short8*)(A + (size_t)(bm + 64 + srow)*lda + kt + scol);
    short8 w0 = *(const short8*)(W + (size_t)(bn + srow)*ldw      + kt + scol);
    short8 w1 = *(const short8*)(W + (size_t)(bn + 64 + srow)*ldw + kt + scol);
    __syncthreads();
    *(short8*)&As[srow*32 + scol]      = a0;
    *(short8*)&As[(64+srow)*32 + scol] = a1;
    *(short8*)&Ws[srow*32 + scol]      = w0;
    *(short8*)&Ws[(64+srow)*32 + scol] = w1;
    __syncthreads();
    short8 af[4], wf[4];
    #pragma unroll
    for (int m=0;m<4;m++) af[m] = *(const short8*)&As[(wr + m*16 + rl)*32 + rg];
    #pragma unroll
    for (int n=0;n<4;n++) wf[n] = *(const short8*)&Ws[(wc + n*16 + rl)*32 + rg];
    #pragma unroll
    for (int m=0;m<4;m++)
      #pragma unroll
      for (int n=0;n<4;n++)
        acc[m][n] = __builtin_amdgcn_mfma_f32_16x16x32_bf16(af[m], wf[n], acc[m][n], 0, 0, 0);
  }

  if (EPI == 0){
    float bv[4];
    #pragma unroll
    for (int n=0;n<4;n++) bv[n] = bias[bn + wc + n*16 + rl];
    #pragma unroll
    for (int m=0;m<4;m++){
      #pragma unroll
      for (int j=0;j<4;j++){
        int r = bm + wr + m*16 + (lane>>4)*4 + j;
        #pragma unroll
        for (int n=0;n<4;n++){
          int c = bn + wc + n*16 + rl;
          C[(size_t)r*ldc + c] = acc[m][n][j] + bv[n];
        }
      }
    }
  } else {
    #pragma unroll
    for (int m=0;m<4;m++){
      #pragma unroll
      for (int j=0;j<4;j++){
        int r = bm + wr + m*16 + (lane>>4)*4 + j;
        int tok = tokRow[r];
        float esum = 0.f;
        #pragma unroll
        for (int n=0;n<4;n++){
          int c = bn + wc + n*16 + rl;
          float v = acc[m][n][j];
          if (c == tok) logitTgt[r] = v;
          esum += __expf(v);
        }
        esum += __shfl_xor(esum, 1);
        esum += __shfl_xor(esum, 2);
        esum += __shfl_xor(esum, 4);
        esum += __shfl_xor(esum, 8);
        if (rl == 0) atomicAdd(&rowSum[r], esum);
      }
    }
  }
}

// ---------------- persistent encoder+decoder megakernel ----------------
// bf16 weights (L2-resident: barrier does NO cache maintenance).
// Cross-block state: write-once per-step slots, agent stores + normal loads.
__global__ __launch_bounds__(TPB, 2) void megakernel(
    const float* __restrict__ preZe, const float* __restrict__ preZd,
    const unsigned short* __restrict__ ehh0b,
    const unsigned short* __restrict__ eih1b, const unsigned short* __restrict__ ehh1b,
    const float* __restrict__ eb1,
    const unsigned short* __restrict__ dih0Hb, const unsigned short* __restrict__ dhh0b,
    const unsigned short* __restrict__ dih1b, const unsigned short* __restrict__ dhh1b,
    const float* __restrict__ db1,
    const unsigned short* __restrict__ Whtb, const float* __restrict__ w2pt,
    const unsigned short* __restrict__ Wctb,
    const int* __restrict__ elen,
    float* __restrict__ h0t_buf,   // [128][B][H]  slot t (enc) / 64+t (dec)
    float* __restrict__ h0c_buf,   // [65][B][H]   enc committed h0 (slot0 = zero)
    float* __restrict__ h1c_buf,   // [65][B][H]   enc committed h1 (slot0 = zero)
    float* __restrict__ ht_buf,    // [65][B][H]   attentional ht (slot0 = zero)
    float* __restrict__ yt_buf,    // [64][B][H]   dec h1 outputs
    float* __restrict__ ct_buf,    // [64][B][H]
    float* __restrict__ tanv_buf,  // [64][B][H]
    float* __restrict__ sc_buf,    // [64][B*S]
    float* __restrict__ c0, float* __restrict__ c1,
    float* __restrict__ c0t,
    float* __restrict__ ench,      // [S][B][H]
    unsigned short* __restrict__ decoutb,
    unsigned* cnt, unsigned* gen)
{
  const int tid  = threadIdx.x;
  const int lane = tid & 63;
  const int gw   = blockIdx.x*(TPB/64) + (tid >> 6);   // 0..2047
  const int j    = gw >> 1;                            // hidden unit
  const int bb   = (gw & 1) * 16;                      // batch half
  const size_t ST = (size_t)BSZ*HDIM;
  const int ks = lane*16;

  // =============== encoder ===============
  for (int t = 0; t < S_LEN; t++){
    // ---- E0 ----
    {
      float4 w[4][4];
      #pragma unroll
      for (int g=0; g<4; g++) ld16bf(ehh0b + ((size_t)(g*HDIM + j))*HDIM + ks, w[g]);
      const float* hsrc = h0c_buf + (size_t)t*ST;
      float* h0tS = h0t_buf + (size_t)t*ST;
      for (int ib=0; ib<16; ib++){
        const int b = bb + ib;
        float pz0=0,pz1=0,pz2=0,pz3=0,cv=0;
        if (lane == 0){
          const float* pz = preZe + ((size_t)(t*BSZ + b))*FOURH + j;
          pz0 = pz[0]; pz1 = pz[HDIM]; pz2 = pz[2*HDIM]; pz3 = pz[3*HDIM];
          cv = c0[b*HDIM + j];
        }
        const float* hp = hsrc + b*HDIM + ks;
        float4 hv[4];
        #pragma unroll
        for (int q=0;q<4;q++) hv[q] = *(const float4*)(hp + q*4);
        float s0=0,s1=0,s2=0,s3=0;
        #pragma unroll
        for (int q=0;q<4;q++){
          s0 += w[0][q].x*hv[q].x + w[0][q].y*hv[q].y + w[0][q].z*hv[q].z + w[0][q].w*hv[q].w;
          s1 += w[1][q].x*hv[q].x + w[1][q].y*hv[q].y + w[1][q].z*hv[q].z + w[1][q].w*hv[q].w;
          s2 += w[2][q].x*hv[q].x + w[2][q].y*hv[q].y + w[2][q].z*hv[q].z + w[2][q].w*hv[q].w;
          s3 += w[3][q].x*hv[q].x + w[3][q].y*hv[q].y + w[3][q].z*hv[q].z + w[3][q].w*hv[q].w;
        }
        s0 = allred(s0); s1 = allred(s1); s2 = allred(s2); s3 = allred(s3);
        if (lane == 0){
          float cc = sigm(pz1+s1)*cv + sigm(pz0+s0)*tanhf(pz2+s2);
          float hh = sigm(pz3+s3)*tanhf(cc);
          stc(&h0tS[b*HDIM + j], hh);
          c0t[b*HDIM + j] = cc;
        }
      }
    }
    gbar(cnt, gen);
    // ---- E1 + masked commit ----
    {
      float4 wi[4][4], wh[4][4];
      #pragma unroll
      for (int g=0; g<4; g++){
        ld16bf(eih1b + ((size_t)(g*HDIM + j))*HDIM + ks, wi[g]);
        ld16bf(ehh1b + ((size_t)(g*HDIM + j))*HDIM + ks, wh[g]);
      }
      float b0=0,b1=0,b2=0,b3=0;
      if (lane == 0){ b0=eb1[j]; b1=eb1[HDIM+j]; b2=eb1[2*HDIM+j]; b3=eb1[3*HDIM+j]; }
      const float* xsrc_ = h0t_buf + (size_t)t*ST;
      const float* hsrc  = h1c_buf + (size_t)t*ST;
      const float* h0prv = h0c_buf + (size_t)t*ST;
      float* h1nS = h1c_buf + (size_t)(t+1)*ST;
      float* h0nS = h0c_buf + (size_t)(t+1)*ST;
      for (int ib=0; ib<16; ib++){
        const int b = bb + ib;
        float c1v=0, h0tv=0, c0tv=0; int lenb=0;
        if (lane == 0){
          size_t bi = (size_t)b*HDIM + j;
          c1v = c1[bi]; h0tv = xsrc_[bi]; c0tv = c0t[bi]; lenb = elen[b];
        }
        const float* xp = xsrc_ + b*HDIM + ks;
        const float* hp = hsrc  + b*HDIM + ks;
        float4 xv[4], hv[4];
        #pragma unroll
        for (int q=0;q<4;q++){ xv[q] = *(const float4*)(xp + q*4); hv[q] = *(const float4*)(hp + q*4); }
        float s0=0,s1=0,s2=0,s3=0;
        #pragma unroll
        for (int q=0;q<4;q++){
          s0 += wi[0][q].x*xv[q].x + wi[0][q].y*xv[q].y + wi[0][q].z*xv[q].z + wi[0][q].w*xv[q].w
              + wh[0][q].x*hv[q].x + wh[0][q].y*hv[q].y + wh[0][q].z*hv[q].z + wh[0][q].w*hv[q].w;
          s1 += wi[1][q].x*xv[q].x + wi[1][q].y*xv[q].y + wi[1][q].z*xv[q].z + wi[1][q].w*xv[q].w
              + wh[1][q].x*hv[q].x + wh[1][q].y*hv[q].y + wh[1][q].z*hv[q].z + wh[1][q].w*hv[q].w;
          s2 += wi[2][q].x*xv[q].x + wi[2][q].y*xv[q].y + wi[2][q].z*xv[q].z + wi[2][q].w*xv[q].w
              + wh[2][q].x*hv[q].x + wh[2][q].y*hv[q].y + wh[2][q].z*hv[q].z + wh[2][q].w*hv[q].w;
          s3 += wi[3][q].x*xv[q].x + wi[3][q].y*xv[q].y + wi[3][q].z*xv[q].z + wi[3][q].w*xv[q].w
              + wh[3][q].x*hv[q].x + wh[3][q].y*hv[q].y + wh[3][q].z*hv[q].z + wh[3][q].w*hv[q].w;
        }
        s0 = allred(s0); s1 = allred(s1); s2 = allred(s2); s3 = allred(s3);
        if (lane == 0){
          float cc = sigm(b1+s1)*c1v + sigm(b0+s0)*tanhf(b2+s2);
          float hh = sigm(b3+s3)*tanhf(cc);
          size_t bi = (size_t)b*HDIM + j;
          if (t < lenb){
            stc(&h1nS[bi], hh); stc(&h0nS[bi], h0tv);
            c1[bi] = cc; c0[bi] = c0tv;
            stc(&ench[((size_t)t*BSZ + b)*HDIM + j], hh);
          } else {
            stc(&h1nS[bi], hsrc[bi]); stc(&h0nS[bi], h0prv[bi]);
            stc(&ench[((size_t)t*BSZ + b)*HDIM + j], 0.f);
          }
        }
      }
    }
    gbar(cnt, gen);
  }

  // =============== decoder ===============
  for (int t = 0; t < T_LEN; t++){
    const float* htsrc = ht_buf + (size_t)t*ST;
    const float* h0prv = (t == 0) ? (h0c_buf + (size_t)64*ST) : (h0t_buf + (size_t)(64+t-1)*ST);
    const float* yprv  = (t == 0) ? (h1c_buf + (size_t)64*ST) : (yt_buf + (size_t)(t-1)*ST);
    float* h0tS = h0t_buf + (size_t)(64+t)*ST;
    float* ytS  = yt_buf + (size_t)t*ST;
    float* tvS  = tanv_buf + (size_t)t*ST;
    float* scS  = sc_buf + (size_t)t*(BSZ*S_LEN);
    float* ctS  = ct_buf + (size_t)t*ST;

    // ---- D0 ----
    {
      float4 wi[4][4], wh[4][4];
      #pragma unroll
      for (int g=0; g<4; g++){
        ld16bf(dih0Hb + ((size_t)(g*HDIM + j))*HDIM + ks, wi[g]);
        ld16bf(dhh0b  + ((size_t)(g*HDIM + j))*HDIM + ks, wh[g]);
      }
      for (int ib=0; ib<16; ib++){
        const int b = bb + ib;
        float pz0=0,pz1=0,pz2=0,pz3=0,cv=0;
        if (lane == 0){
          const float* pz = preZd + ((size_t)(t*BSZ + b))*FOURH + j;
          pz0 = pz[0]; pz1 = pz[HDIM]; pz2 = pz[2*HDIM]; pz3 = pz[3*HDIM];
          cv = c0[b*HDIM + j];
        }
        const float* xp = htsrc + b*HDIM + ks;
        const float* hp = h0prv + b*HDIM + ks;
        float4 xv[4], hv[4];
        #pragma unroll
        for (int q=0;q<4;q++){ xv[q] = *(const float4*)(xp + q*4); hv[q] = *(const float4*)(hp + q*4); }
        float s0=0,s1=0,s2=0,s3=0;
        #pragma unroll
        for (int q=0;q<4;q++){
          s0 += wi[0][q].x*xv[q].x + wi[0][q].y*xv[q].y + wi[0][q].z*xv[q].z + wi[0][q].w*xv[q].w
              + wh[0][q].x*hv[q].x + wh[0][q].y*hv[q].y + wh[0][q].z*hv[q].z + wh[0][q].w*hv[q].w;
          s1 += wi[1][q].x*xv[q].x + wi[1][q].y*xv[q].y + wi[1][q].z*xv[q].z + wi[1][q].w*xv[q].w
              + wh[1][q].x*hv[q].x + wh[1][q].y*hv[q].y + wh[1][q].z*hv[q].z + wh[1][q].w*hv[q].w;
          s2 += wi[2][q].x*xv[q].x + wi[2][q].y*xv[q].y + wi[2][q].z*xv[q].z + wi[2][q].w*xv[q].w
              + wh[2][q].x*hv[q].x + wh[2][q].y*hv[q].y + wh[2][q].z*hv[q].z + wh[2][q].w*hv[q].w;
          s3 += wi[3][q].x*xv[q].x + wi[3][q].y*xv[q].y + wi[3][q].z*xv[q].z + wi[3][q].w*xv[q].w
              + wh[3][q].x*hv[q].x + wh[3][q].y*hv[q].y + wh[3][q].z*hv[q].z + wh[3][q].w*hv[q].w;
        }
        s0 = allred(s0); s1 = allred(s1); s2 = allred(s2); s3 = allred(s3);
        if (lane == 0){
          float cc = sigm(pz1+s1)*cv + sigm(pz0+s0)*tanhf(pz2+s2);
          float hh = sigm(pz3+s3)*tanhf(cc);
          stc(&h0tS[b*HDIM + j], hh);
          c0t[b*HDIM + j] = cc;
        }
      }
    }
    gbar(cnt, gen);
    // ---- D1 (h1 = yt) ----
    {
      float4 wi[4][4], wh[4][4];
      #pragma unroll
      for (int g=0; g<4; g++){
        ld16bf(dih1b + ((size_t)(g*HDIM + j))*HDIM + ks, wi[g]);
        ld16bf(dhh1b + ((size_t)(g*HDIM + j))*HDIM + ks, wh[g]);
      }
      float b0=0,b1=0,b2=0,b3=0;
      if (lane == 0){ b0=db1[j]; b1=db1[HDIM+j]; b2=db1[2*HDIM+j]; b3=db1[3*HDIM+j]; }
      for (int ib=0; ib<16; ib++){
        const int b = bb + ib;
        float c1v=0, c0tv=0;
        if (lane == 0){
          size_t bi = (size_t)b*HDIM + j;
          c1v = c1[bi]; c0tv = c0t[bi];
        }
        const float* xp = h0tS + b*HDIM + ks;
        const float* hp = yprv + b*HDIM + ks;
        float4 xv[4], hv[4];
        #pragma unroll
        for (int q=0;q<4;q++){ xv[q] = *(const float4*)(xp + q*4); hv[q] = *(const float4*)(hp + q*4); }
        float s0=0,s1=0,s2=0,s3=0;
        #pragma unroll
        for (int q=0;q<4;q++){
          s0 += wi[0][q].x*xv[q].x + wi[0][q].y*xv[q].y + wi[0][q].z*xv[q].z + wi[0][q].w*xv[q].w
              + wh[0][q].x*hv[q].x + wh[0][q].y*hv[q].y + wh[0][q].z*hv[q].z + wh[0][q].w*hv[q].w;
          s1 += wi[1][q].x*xv[q].x + wi[1][q].y*xv[q].y + wi[1][q].z*xv[q].z + wi[1][q].w*xv[q].w
              + wh[1][q].x*hv[q].x + wh[1][q].y*hv[q].y + wh[1][q].z*hv[q].z + wh[1][q].w*hv[q].w;
          s2 += wi[2][q].x*xv[q].x + wi[2][q].y*xv[q].y + wi[2][q].z*xv[q].z + wi[2][q].w*xv[q].w
              + wh[2][q].x*hv[q].x + wh[2][q].y*hv[q].y + wh[2][q].z*hv[q].z + wh[2][q].w*hv[q].w;
          s3 += wi[3][q].x*xv[q].x + wi[3][q].y*xv[q].y + wi[3][q].z*xv[q].z + wi[3][q].w*xv[q].w
              + wh[3][q].x*hv[q].x + wh[3][q].y*hv[q].y + wh[3][q].z*hv[q].z + wh[3][q].w*hv[q].w;
        }
        s0 = allred(s0); s1 = allred(s1); s2 = allred(s2); s3 = allred(s3);
        if (lane == 0){
          float cc = sigm(b1+s1)*c1v + sigm(b0+s0)*tanhf(b2+s2);
          float hh = sigm(b3+s3)*tanhf(cc);
          size_t bi = (size_t)b*HDIM + j;
          c1[bi] = cc; c0[bi] = c0tv;
          stc(&ytS[bi], hh);
        }
      }
    }
    gbar(cnt, gen);
    // ---- A: tanv + scores ----
    {
      {
        const int b2 = gw >> 6, s2 = gw & 63;
        int lenb = 0;
        if (lane == 0) lenb = elen[b2];
        const float* yp = ytS + b2*HDIM + ks;
        const float* ep = ench + ((size_t)s2*BSZ + b2)*HDIM + ks;
        float s = 0;
        #pragma unroll
        for (int q=0;q<4;q++){
          float4 yv = *(const float4*)(yp + q*4);
          float4 ev = *(const float4*)(ep + q*4);
          s += yv.x*ev.x + yv.y*ev.y + yv.z*ev.z + yv.w*ev.w;
        }
        s = allred(s);
        if (lane == 0) stc(&scS[b2*S_LEN + s2], (s2 < lenb) ? s : -1e30f);
      }
      {
        float4 w[4];
        ld16bf(Whtb + (size_t)j*HDIM + ks, w);
        for (int ib=0; ib<16; ib++){
          const int b = bb + ib;
          const float* hp = ytS + b*HDIM + ks;
          float s = 0;
          #pragma unroll
          for (int q=0;q<4;q++){
            float4 hv = *(const float4*)(hp + q*4);
            s += w[q].x*hv.x + w[q].y*hv.y + w[q].z*hv.z + w[q].w*hv.w;
          }
          s = allred(s);
          if (lane == 0) stc(&tvS[b*HDIM + j], tanhf(s));
        }
      }
    }
    gbar(cnt, gen);
    // ---- B: pt + softmax + window -> ct ----
    if (gw < 512){
      const int b = gw >> 4;
      const int hb = (gw & 15) * 64;
      float part = 0;
      const float* tv = tvS + b*HDIM + ks;
      const float* wp = w2pt + ks;
      #pragma unroll
      for (int q=0;q<4;q++){
        float4 a = *(const float4*)(tv + q*4);
        float4 c = *(const float4*)(wp + q*4);
        part += a.x*c.x + a.y*c.y + a.z*c.z + a.w*c.w;
      }
      part = allred(part);
      float ptv = sigm(part) * (float)elen[b];
      float sc = scS[b*S_LEN + lane];
      float m = allmax(sc);
      float e = __expf(sc - m);
      float ssum = allred(e);
      float d = (float)lane - ptv;
      float atl = (e/ssum) * __expf(-(d*d)*0.02f);   // WIN_D^2/2 = 50
      float acc = 0;
      #pragma unroll 4
      for (int s = 0; s < S_LEN; s++){
        float a = __shfl(atl, s);
        acc += a * ench[((size_t)s*BSZ + b)*HDIM + hb + lane];
      }
      stc(&ctS[b*HDIM + hb + lane], acc);
    }
    gbar(cnt, gen);
    // ---- C: ht = tanh(cat(ct,yt)*Wct^T) ----
    {
      float4 wc_[4], wy_[4];
      ld16bf(Wctb + (size_t)j*(2*HDIM) + ks, wc_);
      ld16bf(Wctb + (size_t)j*(2*HDIM) + HDIM + ks, wy_);
      float* htn = ht_buf + (size_t)(t+1)*ST;
      for (int ib=0; ib<16; ib++){
        const int b = bb + ib;
        const float* cp = ctS + b*HDIM + ks;
        const float* yp = ytS + b*HDIM + ks;
        float s = 0;
        #pragma unroll
        for (int q=0;q<4;q++){
          float4 cv = *(const float4*)(cp + q*4);
          float4 yv = *(const float4*)(yp + q*4);
          s += wc_[q].x*cv.x + wc_[q].y*cv.y + wc_[q].z*cv.z + wc_[q].w*cv.w
             + wy_[q].x*yv.x + wy_[q].y*yv.y + wy_[q].z*yv.z + wy_[q].w*yv.w;
        }
        s = allred(s);
        if (lane == 0){
          float v = tanhf(s);
          stc(&htn[(size_t)b*HDIM + j], v);
          decoutb[((size_t)t*BSZ + b)*HDIM + j] = f2bf(v);
        }
      }
    }
    gbar(cnt, gen);
  }
}

// ---------------- final loss ----------------
__global__ void loss_kernel(const float* __restrict__ rowSum, const float* __restrict__ logitTgt,
                            const int* __restrict__ tgt, float* __restrict__ out)
{
  const int b = blockIdx.x, t = threadIdx.x;  // 64 threads
  float v = 0.f;
  if (t < T_LEN-1){
    int r = t*BSZ + b;
    if (tgt[(t+1)*BSZ + b] != 0) v = logitTgt[r] - logf(rowSum[r]);
  }
  #pragma unroll
  for (int off=1; off<64; off<<=1) v += __shfl_xor(v, off);
  if (t == 0) out[b] = v;
}

// =====================================================================================
extern "C" void kernel_launch(void* const* d_in, const int* in_sizes, int n_in,
                              void* d_out, int out_size, void* d_ws, size_t ws_size,
                              hipStream_t stream)
{
  const int*   src_tokens = (const int*)d_in[0];
  const int*   tgt_tokens = (const int*)d_in[1];
  const int*   encode_len = (const int*)d_in[2];
  const float* emb_src  = (const float*)d_in[3];
  const float* emb_tar  = (const float*)d_in[4];
  const float* eW_ih0   = (const float*)d_in[5];
  const float* eW_hh0   = (const float*)d_in[6];
  const float* eb0      = (const float*)d_in[7];
  const float* eW_ih1   = (const float*)d_in[8];
  const float* eW_hh1   = (const float*)d_in[9];
  const float* eb1      = (const float*)d_in[10];
  const float* dW_ih0   = (const float*)d_in[11];
  const float* dW_hh0   = (const float*)d_in[12];
  const float* db0      = (const float*)d_in[13];
  const float* dW_ih1   = (const float*)d_in[14];
  const float* dW_hh1   = (const float*)d_in[15];
  const float* db1      = (const float*)d_in[16];
  const float* W_ht2tan = (const float*)d_in[17];
  const float* w_tan2pt = (const float*)d_in[18];
  const float* W_ct2ht  = (const float*)d_in[19];
  const float* W_final  = (const float*)d_in[20];
  float* out = (float*)d_out;

  char* wsp = (char*)d_ws;
  auto alloc = [&](size_t bytes)->void*{
    void* p = (void*)wsp; wsp += ((bytes + 255) & ~(size_t)255); return p;
  };
  const size_t ST = (size_t)BSZ*HDIM;

  float* preZe = (float*)alloc(2048ull*4096*4);
  float* preZd = (float*)alloc(2048ull*4096*4);
  float* ench  = (float*)alloc((size_t)S_LEN*BSZ*HDIM*4);
  float* h0t_buf = (float*)alloc(128ull*ST*4);
  float* h0c_buf = (float*)alloc(65ull*ST*4);
  float* h1c_buf = (float*)alloc(65ull*ST*4);
  float* ht_buf  = (float*)alloc(65ull*ST*4);
  float* yt_buf  = (float*)alloc(64ull*ST*4);
  float* ct_buf  = (float*)alloc(64ull*ST*4);
  float* tanv_buf= (float*)alloc(64ull*ST*4);
  float* sc_buf  = (float*)alloc(64ull*BSZ*S_LEN*4);
  float* c0    = (float*)alloc(ST*4);
  float* c1    = (float*)alloc(ST*4);
  float* c0t   = (float*)alloc(ST*4);
  float* rowSum   = (float*)alloc(2048*4);
  float* logitTgt = (float*)alloc(2048*4);
  int*   tokRow   = (int*)alloc(2048*4);
  unsigned* barws = (unsigned*)alloc(256);
  unsigned short* xsrc    = (unsigned short*)alloc(2048ull*EDIM*2);
  unsigned short* ytgt    = (unsigned short*)alloc(2048ull*EDIM*2);
  unsigned short* eWih0b  = (unsigned short*)alloc((size_t)FOURH*EDIM*2);
  unsigned short* dWih0b  = (unsigned short*)alloc((size_t)FOURH*(EDIM+HDIM)*2);
  unsigned short* Wfinb   = (unsigned short*)alloc((size_t)VDIM*HDIM*2);
  unsigned short* decoutb = (unsigned short*)alloc(2048ull*HDIM*2);
  // bf16 recurrent weights
  unsigned short* ehh0b  = (unsigned short*)alloc((size_t)FOURH*HDIM*2);
  unsigned short* eih1b  = (unsigned short*)alloc((size_t)FOURH*HDIM*2);
  unsigned short* ehh1b  = (unsigned short*)alloc((size_t)FOURH*HDIM*2);
  unsigned short* dih0Hb = (unsigned short*)alloc((size_t)FOURH*HDIM*2);
  unsigned short* dhh0b  = (unsigned short*)alloc((size_t)FOURH*HDIM*2);
  unsigned short* dih1b  = (unsigned short*)alloc((size_t)FOURH*HDIM*2);
  unsigned short* dhh1b  = (unsigned short*)alloc((size_t)FOURH*HDIM*2);
  unsigned short* Whtb   = (unsigned short*)alloc((size_t)HDIM*HDIM*2);
  unsigned short* Wctb   = (unsigned short*)alloc((size_t)HDIM*2*HDIM*2);

  // zero-init: t=-1 slots, c-states, rowSum, barrier
  hipMemsetAsync(h0c_buf, 0, ST*4, stream);
  hipMemsetAsync(h1c_buf, 0, ST*4, stream);
  hipMemsetAsync(ht_buf,  0, ST*4, stream);
  hipMemsetAsync(c0, 0, ST*4, stream);
  hipMemsetAsync(c1, 0, ST*4, stream);
  hipMemsetAsync(rowSum, 0, 2048*4, stream);
  hipMemsetAsync(barws, 0, 256, stream);

  // weight conversions + embedding gathers
  cvt_bf16_v4<<<1024, 256, 0, stream>>>(eW_ih0, eWih0b, (long)FOURH*EDIM/4);
  cvt_bf16_v4<<<2048, 256, 0, stream>>>(dW_ih0, dWih0b, (long)FOURH*(EDIM+HDIM)/4);
  cvt_bf16_v4<<<4096, 256, 0, stream>>>(W_final, Wfinb, (long)VDIM*HDIM/4);
  cvt_bf16_v4<<<2048, 256, 0, stream>>>(eW_hh0, ehh0b, (long)FOURH*HDIM/4);
  cvt_bf16_v4<<<2048, 256, 0, stream>>>(eW_ih1, eih1b, (long)FOURH*HDIM/4);
  cvt_bf16_v4<<<2048, 256, 0, stream>>>(eW_hh1, ehh1b, (long)FOURH*HDIM/4);
  cvt_bf16_v4<<<2048, 256, 0, stream>>>(dW_hh0, dhh0b, (long)FOURH*HDIM/4);
  cvt_bf16_v4<<<2048, 256, 0, stream>>>(dW_ih1, dih1b, (long)FOURH*HDIM/4);
  cvt_bf16_v4<<<2048, 256, 0, stream>>>(dW_hh1, dhh1b, (long)FOURH*HDIM/4);
  cvt_bf16_strided<<<2048, 256, 0, stream>>>(dW_ih0, EDIM+HDIM, EDIM, dih0Hb, HDIM,
                                             (long)FOURH*HDIM/4, HDIM/4);
  cvt_bf16_v4<<<1024, 256, 0, stream>>>(W_ht2tan, Whtb, (long)HDIM*HDIM/4);
  cvt_bf16_v4<<<1024, 256, 0, stream>>>(W_ct2ht, Wctb, (long)HDIM*2*HDIM/4);
  embed_gather<<<(2048*EDIM/4 + 255)/256, 256, 0, stream>>>(src_tokens, emb_src, xsrc, 2048*EDIM/4);
  embed_gather<<<(2048*EDIM/4 + 255)/256, 256, 0, stream>>>(tgt_tokens, emb_tar, ytgt, 2048*EDIM/4);
  tok_row_kernel<<<8, 256, 0, stream>>>(tgt_tokens, tokRow);

  // input projections (bias fused)
  gemm_mfma<0><<<dim3(16,32), 256, 0, stream>>>(xsrc, EDIM, eWih0b, EDIM, eb0,
                                                preZe, FOURH, EDIM, nullptr, nullptr, nullptr);
  gemm_mfma<0><<<dim3(16,32), 256, 0, stream>>>(ytgt, EDIM, dWih0b, EDIM+HDIM, db0,
                                                preZd, FOURH, EDIM, nullptr, nullptr, nullptr);

  // persistent encoder + decoder
  megakernel<<<NBLK, TPB, 0, stream>>>(
      preZe, preZd, ehh0b, eih1b, ehh1b, eb1,
      dih0Hb, dhh0b, dih1b, dhh1b, db1,
      Whtb, w_tan2pt, Wctb, encode_len,
      h0t_buf, h0c_buf, h1c_buf, ht_buf, yt_buf, ct_buf, tanv_buf, sc_buf,
      c0, c1, c0t, ench, decoutb,
      barws + 0, barws + 32);

  // final projection + fused logsumexp
  gemm_mfma<1><<<dim3(16,250), 256, 0, stream>>>(decoutb, HDIM, Wfinb, HDIM, nullptr,
                                                 nullptr, 0, HDIM, rowSum, logitTgt, tokRow);
  loss_kernel<<<32, 64, 0, stream>>>(rowSum, logitTgt, tgt_tokens, out);
}